// Round 6
// baseline (493.176 us; speedup 1.0000x reference)
//
#include <hip/hip_runtime.h>

#define DI __device__ __forceinline__

typedef __attribute__((ext_vector_type(8))) __bf16 bf16x8;
typedef __attribute__((ext_vector_type(4))) float f32x4;

DI unsigned short f2bf(float x) {
  union { float f; unsigned u; } v; v.f = x;
  unsigned r = v.u + 0x7fffu + ((v.u >> 16) & 1u);
  return (unsigned short)(r >> 16);
}
DI float bf2f(unsigned short h) {
  union { unsigned u; float f; } v; v.u = ((unsigned)h) << 16;
  return v.f;
}
DI unsigned pack2(float a, float b) {
  return (unsigned)f2bf(a) | (((unsigned)f2bf(b)) << 16);
}

// Async global->LDS DMA, 16B per lane.
DI void gl_lds16(const void* g, void* l) {
  __builtin_amdgcn_global_load_lds(
      (const __attribute__((address_space(1))) void*)g,
      (__attribute__((address_space(3))) void*)l, 16, 0, 0);
}

// Counted waits (T4): keep prefetch loads in flight across raw s_barrier.
DI void wt_vm0()  { asm volatile("s_waitcnt vmcnt(0) lgkmcnt(0)" ::: "memory"); }
DI void wt_vm6()  { asm volatile("s_waitcnt vmcnt(6) lgkmcnt(0)" ::: "memory"); }
DI void wt_vm8()  { asm volatile("s_waitcnt vmcnt(8) lgkmcnt(0)" ::: "memory"); }
DI void wt_vm10() { asm volatile("s_waitcnt vmcnt(10) lgkmcnt(0)" ::: "memory"); }
DI void wt_vm12() { asm volatile("s_waitcnt vmcnt(12) lgkmcnt(0)" ::: "memory"); }

// ---------------------------------------------------------------------------
// PW: one-time weight convert [w_theta(256x512); w_g(256x512)] f32 -> bf16.
// ---------------------------------------------------------------------------
__global__ __launch_bounds__(256) void pw_conv(
    const float* __restrict__ w_theta, const float* __restrict__ w_g,
    unsigned short* __restrict__ wTG)
{
  int e = (blockIdx.x * 256 + threadIdx.x) * 8;
  const float* src = (e < 131072) ? (w_theta + e) : (w_g + (e - 131072));
  float4 a = *(const float4*)src;
  float4 c = *(const float4*)(src + 4);
  uint4 u;
  u.x = pack2(a.x, a.y); u.y = pack2(a.z, a.w);
  u.z = pack2(c.x, c.y); u.w = pack2(c.z, c.w);
  *(uint4*)(wTG + e) = u;
}

// ---------------------------------------------------------------------------
// K1F: conv (theta|g) 128o x 128n tile via bf16 MFMA from raw y.
// Counted-vmcnt pipeline: 3 LDS buffers, raw s_barrier, prefetch loads stay
// in flight across barriers (never drained to 0 in steady state).
// y loads: dwordx4 (4 VMEM/step/thread); Bs write: bank-minimal ds_write_b64.
// Fused SPP pooling epilogue.
// ---------------------------------------------------------------------------
__constant__ int c_RS[18] = {0, 0,21,42, 0,10,21,32,42,53, 0,8,16,24,32,40,48,56};
__constant__ int c_RE[18] = {64, 22,43,64, 11,22,32,43,54,64, 8,16,24,32,40,48,56,64};

__global__ __launch_bounds__(256) void k1f_conv_pool(
    const float* __restrict__ y, const unsigned short* __restrict__ wTG,
    unsigned short* __restrict__ Rbuf)
{
  const int tid = threadIdx.x;
  const int id = blockIdx.x;
  const int tile = (id & 7) * 16 + (id >> 3);   // XCD-chunked, bijective
  const int mb = (tile & 3) * 128;
  const int nbt = tile >> 2;
  const int nb = nbt * 128;
  const int b  = blockIdx.y;
  const int lane = tid & 63, wv = tid >> 6;
  const int wm = (wv & 1) * 64, wn = (wv >> 1) * 64;
  const int l15 = lane & 15, l4 = lane >> 4;

  // per buffer: As [128][32] bf16 8192 B + Bs [128][40] bf16 10240 B
  __shared__ __align__(16) char smem[3 * 18432];   // 55296 B; epi P uses 33280
  float* P = (float*)smem;

  const int c4 = tid & 7, n4 = tid >> 3;   // c-quad, n-quad
  const float* ycol = y + ((size_t)(b * 512)) * 4096 + nb + n4 * 4;

  f32x4 acc[4][4];
  #pragma unroll
  for (int i = 0; i < 4; ++i)
    #pragma unroll
    for (int j = 0; j < 4; ++j) acc[i][j] = f32x4{0.f, 0.f, 0.f, 0.f};

  float xr0[16], xr1[16];
  auto yload = [&](float* xr, int kb) {
    #pragma unroll
    for (int cc = 0; cc < 4; ++cc)
      *(float4*)&xr[cc * 4] =
          *(const float4*)(ycol + (size_t)(kb + c4 * 4 + cc) * 4096);
  };
  auto dmaA = [&](int buf, int kb) {
    unsigned short* As = (unsigned short*)(smem + buf * 18432);
    #pragma unroll
    for (int p = 0; p < 2; ++p) {
      int chunk = (wv * 2 + p) * 64 + lane;
      int row = chunk >> 2, cc16 = chunk & 3;
      gl_lds16(wTG + ((size_t)(mb + row)) * 512 + kb + cc16 * 8,
               As + (wv * 2 + p) * 512);
    }
  };
  auto bwrite = [&](int buf, const float* xr) {
    unsigned short* Bs = (unsigned short*)(smem + buf * 18432 + 8192);
    #pragma unroll
    for (int q = 0; q < 4; ++q) {
      uint2 u;
      u.x = pack2(xr[q], xr[4 + q]);
      u.y = pack2(xr[8 + q], xr[12 + q]);
      *(uint2*)&Bs[(n4 * 4 + q) * 40 + c4 * 4] = u;
    }
  };
  auto mfma_step = [&](int buf) {
    const unsigned short* As = (const unsigned short*)(smem + buf * 18432);
    const unsigned short* Bs = As + 4096;   // +8192 B
    bf16x8 af[4], bfr[4];
    #pragma unroll
    for (int i = 0; i < 4; ++i)
      af[i] = *(const bf16x8*)&As[(wm + i * 16 + l15) * 32 + l4 * 8];
    #pragma unroll
    for (int j = 0; j < 4; ++j)
      bfr[j] = *(const bf16x8*)&Bs[(wn + j * 16 + l15) * 40 + l4 * 8];
    #pragma unroll
    for (int i = 0; i < 4; ++i)
      #pragma unroll
      for (int j = 0; j < 4; ++j)
        acc[i][j] = __builtin_amdgcn_mfma_f32_16x16x32_bf16(af[i], bfr[j], acc[i][j], 0, 0, 0);
  };

  // Prologue: step0 staged, step1 loads in flight.
  yload(xr0, 0);       // Y(0): 4
  dmaA(0, 0);          // D(0): 2
  bwrite(0, xr0);      // compiler waits Y(0) only (D(0) newer, stays in flight)
  yload(xr1, 32);      // Y(1): 4
  #pragma unroll
  for (int t = 0; t < 16; ++t) {
    if (t + 1 < 16) dmaA((t + 1) % 3, (t + 1) * 32);          // D(t+1)
    if (t + 2 < 16) yload((t & 1) ? xr1 : xr0, (t + 2) * 32); // Y(t+2)
    // Need D(t) landed; newer in flight: Y(t+1)+D(t+1)+Y(t+2).
    if (t < 14) wt_vm10();
    else if (t == 14) wt_vm6();
    else wt_vm0();
    __builtin_amdgcn_s_barrier();
    __builtin_amdgcn_sched_barrier(0);
    mfma_step(t % 3);
    if (t + 1 < 16) bwrite((t + 1) % 3, (t & 1) ? xr0 : xr1);
  }

  // Fused pooling epilogue: two passes (n-halves = image rows h, h+1).
  const int hloc = wv >> 1;
  #pragma unroll
  for (int pass = 0; pass < 2; ++pass) {
    __syncthreads();
    if (hloc == pass) {
      #pragma unroll
      for (int i = 0; i < 4; ++i)
        #pragma unroll
        for (int j = 0; j < 4; ++j)
          #pragma unroll
          for (int r = 0; r < 4; ++r)
            P[(wm + i * 16 + l4 * 4 + r) * 65 + j * 16 + l15] = acc[i][j][r];
    }
    __syncthreads();
    const int o = tid & 127;
    size_t rbase = (((size_t)(b * 64 + nbt * 2 + pass)) * 18) * 512 + mb + o;
    if (tid < 128) {
      float b0 = -3.4e38f, b1 = b0, b2 = b0, b3 = b0;
      #pragma unroll
      for (int w = 0; w < 64; ++w) {
        float v = P[o * 65 + w];
        b0 = fmaxf(b0, v);
        if (w < 22) b1 = fmaxf(b1, v);
        if (w >= 21 && w < 43) b2 = fmaxf(b2, v);
        if (w >= 42) b3 = fmaxf(b3, v);
      }
      Rbuf[rbase]           = f2bf(b0);
      Rbuf[rbase + 512]     = f2bf(b1);
      Rbuf[rbase + 2 * 512] = f2bf(b2);
      Rbuf[rbase + 3 * 512] = f2bf(b3);
    } else {
      float s6[6], s8[8];
      #pragma unroll
      for (int i = 0; i < 6; ++i) s6[i] = -3.4e38f;
      #pragma unroll
      for (int i = 0; i < 8; ++i) s8[i] = -3.4e38f;
      constexpr int R6S[6] = {0, 10, 21, 32, 42, 53};
      constexpr int R6E[6] = {11, 22, 32, 43, 54, 64};
      #pragma unroll
      for (int w = 0; w < 64; ++w) {
        float v = P[o * 65 + w];
        #pragma unroll
        for (int i = 0; i < 6; ++i)
          if (w >= R6S[i] && w < R6E[i]) s6[i] = fmaxf(s6[i], v);
        s8[w >> 3] = fmaxf(s8[w >> 3], v);
      }
      #pragma unroll
      for (int i = 0; i < 6; ++i) Rbuf[rbase + (size_t)(4 + i) * 512] = f2bf(s6[i]);
      #pragma unroll
      for (int i = 0; i < 8; ++i) Rbuf[rbase + (size_t)(10 + i) * 512] = f2bf(s8[i]);
    }
  }
}

// ---------------------------------------------------------------------------
// K2F: reduce Rbuf over h within each pyramid h-bin -> Pt/Pg [b][128 s][256].
// ---------------------------------------------------------------------------
__global__ __launch_bounds__(256) void k2_pool_final(
    const unsigned short* __restrict__ Rbuf, float* __restrict__ Pt,
    float* __restrict__ Pg)
{
  const int s = blockIdx.x, b = blockIdx.y, tid = threadIdx.x;
  size_t obase = ((size_t)(b * 128) + s) * 256 + tid;
  if (s >= 110) { Pt[obase] = 0.f; Pg[obase] = 0.f; return; }
  int he, wb;
  if (s == 0)      { he = 0; wb = 0; }
  else if (s < 10) { int i = s - 1;  he = 1 + i / 3;  wb = 1 + i % 3; }
  else if (s < 46) { int i = s - 10; he = 4 + i / 6;  wb = 4 + i % 6; }
  else             { int i = s - 46; he = 10 + i / 8; wb = 10 + i % 8; }
  float m0 = -3.4e38f, m1 = -3.4e38f;
  int e = c_RE[he];
  for (int h = c_RS[he]; h < e; ++h) {
    const unsigned short* r = Rbuf + (((size_t)(b * 64 + h)) * 18 + wb) * 512;
    m0 = fmaxf(m0, bf2f(r[tid]));
    m1 = fmaxf(m1, bf2f(r[tid + 256]));
  }
  Pt[obase] = m0;
  Pg[obase] = m1;
}

// ---------------------------------------------------------------------------
// K3 (fused kmat+vmat, blockIdx.z selects):
//  z=0: Kt[b,s,c] = sum_ic w_phi[ic,c]*Pt[b,s,ic] -> hi/lo bf16 split
//  z=1: Vb[b,o,s] = bf16( sum_ic w_mask[o,ic]*Pg[b,s,ic] )
// ---------------------------------------------------------------------------
__global__ __launch_bounds__(256) void k3_fused(
    const float* __restrict__ Pt, const float* __restrict__ Pg,
    const float* __restrict__ w_phi, const float* __restrict__ w_mask,
    unsigned short* __restrict__ Kth, unsigned short* __restrict__ Ktl,
    unsigned short* __restrict__ Vb)
{
  __shared__ __align__(16) char sm3[51200];
  const int tid = threadIdx.x;
  const int tx = tid & 15, ty = tid >> 4;
  const int b = blockIdx.y;
  if (blockIdx.z == 0) {
    const int ct = blockIdx.x;
    const int c0 = tx * 4, s0 = ty * 8;
    float* Ls = (float*)sm3;            // [128][64]
    float* Ws = Ls + 128 * 64;          // [64][68]
    float acc[8][4] = {};
    for (int kc = 0; kc < 256; kc += 64) {
      #pragma unroll
      for (int j = 0; j < 8; ++j) {
        int flat = tid + 256 * j;
        int row = flat >> 4, k4 = (flat & 15) << 2;
        *(float4*)&Ls[row * 64 + k4] =
            *(const float4*)(Pt + ((size_t)(b * 128) + row) * 256 + kc + k4);
      }
      #pragma unroll
      for (int j = 0; j < 4; ++j) {
        int flat = tid + 256 * j;
        int row = flat >> 4, cc4 = (flat & 15) << 2;
        *(float4*)&Ws[row * 68 + cc4] =
            *(const float4*)(w_phi + (size_t)(kc + row) * 512 + ct * 64 + cc4);
      }
      __syncthreads();
      for (int k = 0; k < 64; k += 4) {
        float4 wv[4];
        #pragma unroll
        for (int kk = 0; kk < 4; ++kk) wv[kk] = *(const float4*)&Ws[(k + kk) * 68 + c0];
        #pragma unroll
        for (int i = 0; i < 8; ++i) {
          float4 a = *(const float4*)&Ls[(s0 + i) * 64 + k];
          const float* ap = (const float*)&a;
          #pragma unroll
          for (int kk = 0; kk < 4; ++kk) {
            const float* wp = (const float*)&wv[kk];
            acc[i][0] += ap[kk] * wp[0];
            acc[i][1] += ap[kk] * wp[1];
            acc[i][2] += ap[kk] * wp[2];
            acc[i][3] += ap[kk] * wp[3];
          }
        }
      }
      __syncthreads();
    }
    #pragma unroll
    for (int i = 0; i < 8; ++i) {
      unsigned short hi[4]; float lo[4];
      #pragma unroll
      for (int j = 0; j < 4; ++j) { hi[j] = f2bf(acc[i][j]); lo[j] = acc[i][j] - bf2f(hi[j]); }
      size_t base = ((size_t)(b * 128) + s0 + i) * 512 + ct * 64 + c0;
      uint2 uh; uh.x = (unsigned)hi[0] | ((unsigned)hi[1] << 16);
      uh.y = (unsigned)hi[2] | ((unsigned)hi[3] << 16);
      uint2 ul; ul.x = pack2(lo[0], lo[1]); ul.y = pack2(lo[2], lo[3]);
      *(uint2*)&Kth[base] = uh;
      *(uint2*)&Ktl[base] = ul;
    }
  } else {
    const int ot = blockIdx.x;
    const int o0 = ty * 4;
    float* Ws = (float*)sm3;            // [64][64]
    float* Ps = Ws + 64 * 64;           // [128][68]
    float acc[4][8] = {};
    for (int kc = 0; kc < 256; kc += 64) {
      #pragma unroll
      for (int j = 0; j < 4; ++j) {
        int flat = tid + 256 * j;
        int row = flat >> 4, k4 = (flat & 15) << 2;
        *(float4*)&Ws[row * 64 + k4] =
            *(const float4*)(w_mask + (size_t)(ot * 64 + row) * 256 + kc + k4);
      }
      #pragma unroll
      for (int j = 0; j < 8; ++j) {
        int flat = tid + 256 * j;
        int row = flat >> 4, k4 = (flat & 15) << 2;
        *(float4*)&Ps[row * 68 + k4] =
            *(const float4*)(Pg + ((size_t)(b * 128) + row) * 256 + kc + k4);
      }
      __syncthreads();
      for (int k = 0; k < 64; k += 4) {
        float4 wv[4];
        #pragma unroll
        for (int i = 0; i < 4; ++i) wv[i] = *(const float4*)&Ws[(o0 + i) * 64 + k];
        #pragma unroll
        for (int jj = 0; jj < 8; ++jj) {
          float4 pv = *(const float4*)&Ps[(tx + 16 * jj) * 68 + k];
          const float* pp = (const float*)&pv;
          #pragma unroll
          for (int i = 0; i < 4; ++i) {
            const float* wp = (const float*)&wv[i];
            #pragma unroll
            for (int kk = 0; kk < 4; ++kk) acc[i][jj] += wp[kk] * pp[kk];
          }
        }
      }
      __syncthreads();
    }
    #pragma unroll
    for (int i = 0; i < 4; ++i)
      #pragma unroll
      for (int jj = 0; jj < 8; ++jj)
        Vb[((size_t)(b * 512) + ot * 64 + o0 + i) * 128 + tx + 16 * jj] =
            f2bf(acc[i][jj]);
  }
}

// ---------------------------------------------------------------------------
// K4: scoresT[b,n,s] = sum_c Kt[b,s,c]*x[b,c,n]; Kt hi/lo split (2 MFMAs).
// Same counted-vmcnt 3-buffer pipeline as k1f (DMA counts: 4/step -> 12/8/0).
// Output transposed [n][s]; epilogue emits per-(s, n-tile) softmax partials.
// ---------------------------------------------------------------------------
__global__ __launch_bounds__(256) void k4_scores(
    const float* __restrict__ x, const unsigned short* __restrict__ Kth,
    const unsigned short* __restrict__ Ktl, float* __restrict__ scoresT,
    float* __restrict__ pmax_g, float* __restrict__ psum_g)
{
  const int tid = threadIdx.x;
  const int ntile = blockIdx.x;
  const int nb = ntile * 128;
  const int b = blockIdx.y;
  const int lane = tid & 63, wv = tid >> 6;
  const int wm = (wv & 1) * 64, wn = (wv >> 1) * 64;
  const int l15 = lane & 15, l4 = lane >> 4;
  // per buffer: Ah 8192 | Al 8192 | Bs [128][40] 10240 -> 26624 B
  __shared__ __align__(16) char smem4[3 * 26624];   // 79872 B
  __shared__ float SmP[256], SsP[256];

  const int c4 = tid & 7, n4 = tid >> 3;
  const float* xcol = x + ((size_t)(b * 512)) * 4096 + nb + n4 * 4;

  f32x4 acc[4][4];
  #pragma unroll
  for (int i = 0; i < 4; ++i)
    #pragma unroll
    for (int j = 0; j < 4; ++j) acc[i][j] = f32x4{0.f, 0.f, 0.f, 0.f};

  float xr0[16], xr1[16];
  auto xload = [&](float* xr, int kb) {
    #pragma unroll
    for (int cc = 0; cc < 4; ++cc)
      *(float4*)&xr[cc * 4] =
          *(const float4*)(xcol + (size_t)(kb + c4 * 4 + cc) * 4096);
  };
  auto dmaA = [&](int buf, int kb) {
    unsigned short* Ah = (unsigned short*)(smem4 + buf * 26624);
    unsigned short* Al = Ah + 4096;
    #pragma unroll
    for (int p = 0; p < 2; ++p) {
      int chunk = (wv * 2 + p) * 64 + lane;
      int row = chunk >> 2, cc16 = chunk & 3;
      size_t g = ((size_t)(b * 128) + row) * 512 + kb + cc16 * 8;
      gl_lds16(Kth + g, Ah + (wv * 2 + p) * 512);
      gl_lds16(Ktl + g, Al + (wv * 2 + p) * 512);
    }
  };
  auto bwrite = [&](int buf, const float* xr) {
    unsigned short* Bs = (unsigned short*)(smem4 + buf * 26624 + 16384);
    #pragma unroll
    for (int q = 0; q < 4; ++q) {
      uint2 u;
      u.x = pack2(xr[q], xr[4 + q]);
      u.y = pack2(xr[8 + q], xr[12 + q]);
      *(uint2*)&Bs[(n4 * 4 + q) * 40 + c4 * 4] = u;
    }
  };
  auto mfma_step = [&](int buf) {
    const unsigned short* Ah = (const unsigned short*)(smem4 + buf * 26624);
    const unsigned short* Al = Ah + 4096;
    const unsigned short* Bs = Al + 4096;
    bf16x8 ah[4], al[4], bfr[4];
    #pragma unroll
    for (int i = 0; i < 4; ++i) {
      ah[i] = *(const bf16x8*)&Ah[(wm + i * 16 + l15) * 32 + l4 * 8];
      al[i] = *(const bf16x8*)&Al[(wm + i * 16 + l15) * 32 + l4 * 8];
    }
    #pragma unroll
    for (int j = 0; j < 4; ++j)
      bfr[j] = *(const bf16x8*)&Bs[(wn + j * 16 + l15) * 40 + l4 * 8];
    #pragma unroll
    for (int i = 0; i < 4; ++i)
      #pragma unroll
      for (int j = 0; j < 4; ++j) {
        acc[i][j] = __builtin_amdgcn_mfma_f32_16x16x32_bf16(ah[i], bfr[j], acc[i][j], 0, 0, 0);
        acc[i][j] = __builtin_amdgcn_mfma_f32_16x16x32_bf16(al[i], bfr[j], acc[i][j], 0, 0, 0);
      }
  };

  xload(xr0, 0);       // Y(0): 4
  dmaA(0, 0);          // D(0): 4
  bwrite(0, xr0);
  xload(xr1, 32);      // Y(1): 4
  #pragma unroll
  for (int t = 0; t < 16; ++t) {
    if (t + 1 < 16) dmaA((t + 1) % 3, (t + 1) * 32);
    if (t + 2 < 16) xload((t & 1) ? xr1 : xr0, (t + 2) * 32);
    if (t < 14) wt_vm12();
    else if (t == 14) wt_vm8();
    else wt_vm0();
    __builtin_amdgcn_s_barrier();
    __builtin_amdgcn_sched_barrier(0);
    mfma_step(t % 3);
    if (t + 1 < 16) bwrite((t + 1) % 3, (t & 1) ? xr0 : xr1);
  }

  // scoresT store: n row = nb+wn+j*16+l15, s base = wm+i*16+l4*4 (float4 in s)
  #pragma unroll
  for (int i = 0; i < 4; ++i)
    #pragma unroll
    for (int j = 0; j < 4; ++j)
      *(float4*)(scoresT + ((size_t)(b * 4096) + nb + wn + j * 16 + l15) * 128 +
                 wm + i * 16 + l4 * 4) = *(float4*)&acc[i][j];

  // Softmax partials for this 128s x 128n tile.
  const int nh = wn >> 6;
  float cm[4][4];
  #pragma unroll
  for (int i = 0; i < 4; ++i)
    #pragma unroll
    for (int r = 0; r < 4; ++r) {
      float v = fmaxf(fmaxf(acc[i][0][r], acc[i][1][r]),
                      fmaxf(acc[i][2][r], acc[i][3][r]));
      v = fmaxf(v, __shfl_xor(v, 1));
      v = fmaxf(v, __shfl_xor(v, 2));
      v = fmaxf(v, __shfl_xor(v, 4));
      v = fmaxf(v, __shfl_xor(v, 8));
      if (l15 == 0) SmP[(wm + i * 16 + l4 * 4 + r) * 2 + nh] = v;
    }
  __syncthreads();
  #pragma unroll
  for (int i = 0; i < 4; ++i)
    #pragma unroll
    for (int r = 0; r < 4; ++r) {
      int s = wm + i * 16 + l4 * 4 + r;
      cm[i][r] = fmaxf(SmP[s * 2], SmP[s * 2 + 1]);
    }
  #pragma unroll
  for (int i = 0; i < 4; ++i)
    #pragma unroll
    for (int r = 0; r < 4; ++r) {
      float s0 = __expf(acc[i][0][r] - cm[i][r]) + __expf(acc[i][1][r] - cm[i][r]) +
                 __expf(acc[i][2][r] - cm[i][r]) + __expf(acc[i][3][r] - cm[i][r]);
      s0 += __shfl_xor(s0, 1);
      s0 += __shfl_xor(s0, 2);
      s0 += __shfl_xor(s0, 4);
      s0 += __shfl_xor(s0, 8);
      if (l15 == 0) SsP[(wm + i * 16 + l4 * 4 + r) * 2 + nh] = s0;
    }
  __syncthreads();
  if (tid < 128) {
    size_t pidx = ((size_t)(b * 128) + tid) * 32 + ntile;
    pmax_g[pidx] = fmaxf(SmP[tid * 2], SmP[tid * 2 + 1]);
    psum_g[pidx] = SsP[tid * 2] + SsP[tid * 2 + 1];
  }
}

// ---------------------------------------------------------------------------
// K5E: combine per-tile partials -> (m, 1/sum) per (b,s), then stream
// Eb[b,n,s] = bf16( exp(scoresT[b,n,s]-m[s]) * linv[s] ).
// ---------------------------------------------------------------------------
__global__ __launch_bounds__(256) void k5e_exp(
    const float* __restrict__ scoresT, const float* __restrict__ pmax_g,
    const float* __restrict__ psum_g, unsigned short* __restrict__ Eb)
{
  const int b = blockIdx.y, tid = threadIdx.x;
  __shared__ float sm[128], sl[128];
  if (tid < 128) {
    float M = 0.f, linv = 0.f;
    if (tid < 110) {
      const float* pm = pmax_g + ((size_t)(b * 128) + tid) * 32;
      const float* ps = psum_g + ((size_t)(b * 128) + tid) * 32;
      M = -3.4e38f;
      #pragma unroll
      for (int t = 0; t < 32; ++t) M = fmaxf(M, pm[t]);
      float S = 0.f;
      #pragma unroll
      for (int t = 0; t < 32; ++t) S += ps[t] * __expf(pm[t] - M);
      linv = 1.f / S;
    }
    sm[tid] = M; sl[tid] = linv;
  }
  __syncthreads();
  const size_t base = (size_t)b * 4096 * 128;
  #pragma unroll
  for (int j = 0; j < 8; ++j) {
    int chunk = blockIdx.x * 2048 + j * 256 + tid;   // float4 id within b
    int sc = (chunk & 31) * 4;
    float4 v = *(const float4*)(scoresT + base + (size_t)chunk * 4);
    float e0 = __expf(v.x - sm[sc])     * sl[sc];
    float e1 = __expf(v.y - sm[sc + 1]) * sl[sc + 1];
    float e2 = __expf(v.z - sm[sc + 2]) * sl[sc + 2];
    float e3 = __expf(v.w - sm[sc + 3]) * sl[sc + 3];
    uint2 u; u.x = pack2(e0, e1); u.y = pack2(e2, e3);
    *(uint2*)(Eb + base + (size_t)chunk * 4) = u;
  }
}

// ---------------------------------------------------------------------------
// K6: out[b,o,n] = sum_s Vb[b,o,s] * Eb[b,n,s] + x[b,o,n]
// Whole K=128 staged at once (ONE barrier); x prefetched into VGPRs while
// the LDS-DMA is in flight. XCD-chunked tile swizzle for Eb L2 reuse.
// ---------------------------------------------------------------------------
__global__ __launch_bounds__(256) void k6_out(
    const unsigned short* __restrict__ Eb, const unsigned short* __restrict__ Vb,
    const float* __restrict__ x, float* __restrict__ out)
{
  const int tid = threadIdx.x;
  const int id = blockIdx.x;
  const int tile = (id & 7) * 16 + (id >> 3);   // XCD-chunked, bijective
  const int mb = (tile & 3) * 128;
  const int nb = (tile >> 2) * 128;
  const int b = blockIdx.y;
  const int lane = tid & 63, wv = tid >> 6;
  const int wm = (wv & 1) * 64, wn = (wv >> 1) * 64;
  const int l15 = lane & 15, l4 = lane >> 4;
  __shared__ __align__(16) unsigned short SA[4][4096];   // 32 KB
  __shared__ __align__(16) unsigned short SB[4][4096];   // 32 KB

  #pragma unroll
  for (int h = 0; h < 4; ++h)
    #pragma unroll
    for (int p = 0; p < 2; ++p) {
      int chunk = (wv * 2 + p) * 64 + lane;
      int row = chunk >> 2, c16 = chunk & 3;
      gl_lds16(Vb + ((size_t)(b * 512) + mb + row) * 128 + h * 32 + c16 * 8,
               &SA[h][(wv * 2 + p) * 512]);
      gl_lds16(Eb + ((size_t)(b * 4096) + nb + row) * 128 + h * 32 + c16 * 8,
               &SB[h][(wv * 2 + p) * 512]);
    }

  float xr[4][4][4];
  #pragma unroll
  for (int i = 0; i < 4; ++i)
    #pragma unroll
    for (int j = 0; j < 4; ++j)
      #pragma unroll
      for (int r = 0; r < 4; ++r)
        xr[i][j][r] = x[((size_t)(b * 512) + mb + wm + i * 16 + l4 * 4 + r) * 4096 +
                        nb + wn + j * 16 + l15];

  f32x4 acc[4][4];
  #pragma unroll
  for (int i = 0; i < 4; ++i)
    #pragma unroll
    for (int j = 0; j < 4; ++j) acc[i][j] = f32x4{0.f, 0.f, 0.f, 0.f};

  __syncthreads();
  #pragma unroll
  for (int h = 0; h < 4; ++h) {
    bf16x8 af[4], bfr[4];
    #pragma unroll
    for (int i = 0; i < 4; ++i)
      af[i] = *(const bf16x8*)&SA[h][(wm + i * 16 + l15) * 32 + l4 * 8];
    #pragma unroll
    for (int j = 0; j < 4; ++j)
      bfr[j] = *(const bf16x8*)&SB[h][(wn + j * 16 + l15) * 32 + l4 * 8];
    #pragma unroll
    for (int i = 0; i < 4; ++i)
      #pragma unroll
      for (int j = 0; j < 4; ++j)
        acc[i][j] = __builtin_amdgcn_mfma_f32_16x16x32_bf16(af[i], bfr[j], acc[i][j], 0, 0, 0);
  }
  #pragma unroll
  for (int i = 0; i < 4; ++i)
    #pragma unroll
    for (int j = 0; j < 4; ++j)
      #pragma unroll
      for (int r = 0; r < 4; ++r) {
        int o = mb + wm + i * 16 + l4 * 4 + r;
        size_t idx = ((size_t)(b * 512) + o) * 4096 + nb + wn + j * 16 + l15;
        out[idx] = acc[i][j][r] + xr[i][j][r];
      }
}

// ---------------------------------------------------------------------------
extern "C" void kernel_launch(void* const* d_in, const int* in_sizes, int n_in,
                              void* d_out, int out_size, void* d_ws, size_t ws_size,
                              hipStream_t stream)
{
  (void)in_sizes; (void)n_in; (void)out_size; (void)ws_size;
  const float* x       = (const float*)d_in[0];
  const float* y       = (const float*)d_in[1];
  const float* w_phi   = (const float*)d_in[2];
  const float* w_theta = (const float*)d_in[3];
  const float* w_g     = (const float*)d_in[4];
  const float* w_mask  = (const float*)d_in[5];
  float* out = (float*)d_out;

  char* ws = (char*)d_ws;
  char* B0 = ws + 67108864;
  unsigned short* Rbuf = (unsigned short*)B0;                 // 18874368 B
  float* scoresT = (float*)B0;                                // 33554432 B (after k2)
  unsigned short* Eb = (unsigned short*)(B0 + 33554432);      // 16777216 B
  unsigned short* wTG = (unsigned short*)(B0 + 50331648);     // 524288 B (pw->k1f)
  unsigned short* Vb  = (unsigned short*)(B0 + 50331648);     // 2097152 B (k3->k6)
  float* pmax_g = (float*)(B0 + 52428800);                    // 262144 B (k4->k5e)
  float* psum_g = (float*)(B0 + 52690944);                    // 262144 B (k4->k5e)
  char* C0 = B0 + 54525952;
  float* Pt = (float*)C0;                                     // 2097152
  float* Pg = (float*)(C0 + 2097152);                         // 2097152
  unsigned short* Kth = (unsigned short*)(C0 + 4194304);      // 2097152
  unsigned short* Ktl = (unsigned short*)(C0 + 6291456);      // 2097152

  pw_conv<<<dim3(128), 256, 0, stream>>>(w_theta, w_g, wTG);
  k1f_conv_pool<<<dim3(128, 16), 256, 0, stream>>>(y, wTG, Rbuf);
  k2_pool_final<<<dim3(128, 16), 256, 0, stream>>>(Rbuf, Pt, Pg);
  k3_fused<<<dim3(8, 16, 2), 256, 0, stream>>>(Pt, Pg, w_phi, w_mask, Kth, Ktl, Vb);
  k4_scores<<<dim3(32, 16), 256, 0, stream>>>(x, Kth, Ktl, scoresT, pmax_g, psum_g);
  k5e_exp<<<dim3(64, 16), 256, 0, stream>>>(scoresT, pmax_g, psum_g, Eb);
  k6_out<<<dim3(128, 16), 256, 0, stream>>>(Eb, Vb, x, out);
}

// Round 7
// 485.520 us; speedup vs baseline: 1.0158x; 1.0158x over previous
//
#include <hip/hip_runtime.h>

#define DI __device__ __forceinline__

typedef __attribute__((ext_vector_type(8))) __bf16 bf16x8;
typedef __attribute__((ext_vector_type(4))) float f32x4;

DI unsigned short f2bf(float x) {
  union { float f; unsigned u; } v; v.f = x;
  unsigned r = v.u + 0x7fffu + ((v.u >> 16) & 1u);
  return (unsigned short)(r >> 16);
}
DI float bf2f(unsigned short h) {
  union { unsigned u; float f; } v; v.u = ((unsigned)h) << 16;
  return v.f;
}
DI unsigned pack2(float a, float b) {
  return (unsigned)f2bf(a) | (((unsigned)f2bf(b)) << 16);
}

// Async global->LDS DMA, 16B per lane.
DI void gl_lds16(const void* g, void* l) {
  __builtin_amdgcn_global_load_lds(
      (const __attribute__((address_space(1))) void*)g,
      (__attribute__((address_space(3))) void*)l, 16, 0, 0);
}

// Counted waits (T4): keep prefetch loads in flight across raw s_barrier.
DI void wt_vm0() { asm volatile("s_waitcnt vmcnt(0) lgkmcnt(0)" ::: "memory"); }
DI void wt_vm4() { asm volatile("s_waitcnt vmcnt(4) lgkmcnt(0)" ::: "memory"); }

// ---------------------------------------------------------------------------
// PW: one-time weight convert [w_theta(256x512); w_g(256x512)] f32 -> bf16.
// ---------------------------------------------------------------------------
__global__ __launch_bounds__(256) void pw_conv(
    const float* __restrict__ w_theta, const float* __restrict__ w_g,
    unsigned short* __restrict__ wTG)
{
  int e = (blockIdx.x * 256 + threadIdx.x) * 8;
  const float* src = (e < 131072) ? (w_theta + e) : (w_g + (e - 131072));
  float4 a = *(const float4*)src;
  float4 c = *(const float4*)(src + 4);
  uint4 u;
  u.x = pack2(a.x, a.y); u.y = pack2(a.z, a.w);
  u.z = pack2(c.x, c.y); u.w = pack2(c.z, c.w);
  *(uint4*)(wTG + e) = u;
}

// ---------------------------------------------------------------------------
// K1F: conv (theta|g) 128o x 128n tile via bf16 MFMA from raw y.
// 2 LDS buffers (36.9 KB -> 4 blocks/CU), counted vmcnt, stage AFTER barrier
// (2-buffer safe), y prefetched 3 tiles ahead (xr[3]). Fused SPP epilogue.
// ---------------------------------------------------------------------------
__constant__ int c_RS[18] = {0, 0,21,42, 0,10,21,32,42,53, 0,8,16,24,32,40,48,56};
__constant__ int c_RE[18] = {64, 22,43,64, 11,22,32,43,54,64, 8,16,24,32,40,48,56,64};

__global__ __launch_bounds__(256) void k1f_conv_pool(
    const float* __restrict__ y, const unsigned short* __restrict__ wTG,
    unsigned short* __restrict__ Rbuf)
{
  const int tid = threadIdx.x;
  const int id = blockIdx.x;
  const int tile = (id & 7) * 16 + (id >> 3);   // XCD-chunked, bijective
  const int mb = (tile & 3) * 128;
  const int nbt = tile >> 2;
  const int nb = nbt * 128;
  const int b  = blockIdx.y;
  const int lane = tid & 63, wv = tid >> 6;
  const int wm = (wv & 1) * 64, wn = (wv >> 1) * 64;
  const int l15 = lane & 15, l4 = lane >> 4;

  // per buffer: As [128][32] bf16 8192 B + Bs [128][40] bf16 10240 B
  __shared__ __align__(16) char smem[2 * 18432];   // 36864 B; epi P uses 33280
  float* P = (float*)smem;

  const int c4 = tid & 7, n4 = tid >> 3;   // c-quad, n-quad
  const float* ycol = y + ((size_t)(b * 512)) * 4096 + nb + n4 * 4;

  f32x4 acc[4][4];
  #pragma unroll
  for (int i = 0; i < 4; ++i)
    #pragma unroll
    for (int j = 0; j < 4; ++j) acc[i][j] = f32x4{0.f, 0.f, 0.f, 0.f};

  float xr[3][16];
  auto yload = [&](float* xrp, int kb) {
    #pragma unroll
    for (int cc = 0; cc < 4; ++cc)
      *(float4*)&xrp[cc * 4] =
          *(const float4*)(ycol + (size_t)(kb + c4 * 4 + cc) * 4096);
  };
  auto dmaA = [&](int buf, int kb) {
    unsigned short* As = (unsigned short*)(smem + buf * 18432);
    #pragma unroll
    for (int p = 0; p < 2; ++p) {
      int chunk = (wv * 2 + p) * 64 + lane;
      int row = chunk >> 2, cc16 = chunk & 3;
      gl_lds16(wTG + ((size_t)(mb + row)) * 512 + kb + cc16 * 8,
               As + (wv * 2 + p) * 512);
    }
  };
  auto bwrite = [&](int buf, const float* xrp) {
    unsigned short* Bs = (unsigned short*)(smem + buf * 18432 + 8192);
    #pragma unroll
    for (int q = 0; q < 4; ++q) {
      uint2 u;
      u.x = pack2(xrp[q], xrp[4 + q]);
      u.y = pack2(xrp[8 + q], xrp[12 + q]);
      *(uint2*)&Bs[(n4 * 4 + q) * 40 + c4 * 4] = u;
    }
  };
  auto mfma_step = [&](int buf) {
    const unsigned short* As = (const unsigned short*)(smem + buf * 18432);
    const unsigned short* Bs = As + 4096;   // +8192 B
    bf16x8 af[4], bfr[4];
    #pragma unroll
    for (int i = 0; i < 4; ++i)
      af[i] = *(const bf16x8*)&As[(wm + i * 16 + l15) * 32 + l4 * 8];
    #pragma unroll
    for (int j = 0; j < 4; ++j)
      bfr[j] = *(const bf16x8*)&Bs[(wn + j * 16 + l15) * 40 + l4 * 8];
    #pragma unroll
    for (int i = 0; i < 4; ++i)
      #pragma unroll
      for (int j = 0; j < 4; ++j)
        acc[i][j] = __builtin_amdgcn_mfma_f32_16x16x32_bf16(af[i], bfr[j], acc[i][j], 0, 0, 0);
  };

  // Prologue: D0 then Y0..Y2; bwrite(0) auto-drains D0+Y0, leaves Y1,Y2.
  dmaA(0, 0);
  yload(xr[0], 0);
  yload(xr[1], 32);
  yload(xr[2], 64);
  bwrite(0, xr[0]);
  #pragma unroll
  for (int t = 0; t < 16; ++t) {
    // Entering (steady): queue Y(t+1)[4], D(t)[2], Y(t+2)[4] -> drain thru D(t).
    if (t < 14) wt_vm4();
    else wt_vm0();
    __builtin_amdgcn_s_barrier();
    __builtin_amdgcn_sched_barrier(0);
    if (t + 1 < 16) dmaA((t + 1) & 1, (t + 1) * 32);     // after barrier: 2-buf safe
    if (t + 3 < 16) yload(xr[t % 3], (t + 3) * 32);
    mfma_step(t & 1);
    if (t + 1 < 16) bwrite((t + 1) & 1, xr[(t + 1) % 3]);
  }

  // Fused pooling epilogue: two passes (n-halves = image rows h, h+1).
  const int hloc = wv >> 1;
  #pragma unroll
  for (int pass = 0; pass < 2; ++pass) {
    __syncthreads();
    if (hloc == pass) {
      #pragma unroll
      for (int i = 0; i < 4; ++i)
        #pragma unroll
        for (int j = 0; j < 4; ++j)
          #pragma unroll
          for (int r = 0; r < 4; ++r)
            P[(wm + i * 16 + l4 * 4 + r) * 65 + j * 16 + l15] = acc[i][j][r];
    }
    __syncthreads();
    const int o = tid & 127;
    size_t rbase = (((size_t)(b * 64 + nbt * 2 + pass)) * 18) * 512 + mb + o;
    if (tid < 128) {
      float b0 = -3.4e38f, b1 = b0, b2 = b0, b3 = b0;
      #pragma unroll
      for (int w = 0; w < 64; ++w) {
        float v = P[o * 65 + w];
        b0 = fmaxf(b0, v);
        if (w < 22) b1 = fmaxf(b1, v);
        if (w >= 21 && w < 43) b2 = fmaxf(b2, v);
        if (w >= 42) b3 = fmaxf(b3, v);
      }
      Rbuf[rbase]           = f2bf(b0);
      Rbuf[rbase + 512]     = f2bf(b1);
      Rbuf[rbase + 2 * 512] = f2bf(b2);
      Rbuf[rbase + 3 * 512] = f2bf(b3);
    } else {
      float s6[6], s8[8];
      #pragma unroll
      for (int i = 0; i < 6; ++i) s6[i] = -3.4e38f;
      #pragma unroll
      for (int i = 0; i < 8; ++i) s8[i] = -3.4e38f;
      constexpr int R6S[6] = {0, 10, 21, 32, 42, 53};
      constexpr int R6E[6] = {11, 22, 32, 43, 54, 64};
      #pragma unroll
      for (int w = 0; w < 64; ++w) {
        float v = P[o * 65 + w];
        #pragma unroll
        for (int i = 0; i < 6; ++i)
          if (w >= R6S[i] && w < R6E[i]) s6[i] = fmaxf(s6[i], v);
        s8[w >> 3] = fmaxf(s8[w >> 3], v);
      }
      #pragma unroll
      for (int i = 0; i < 6; ++i) Rbuf[rbase + (size_t)(4 + i) * 512] = f2bf(s6[i]);
      #pragma unroll
      for (int i = 0; i < 8; ++i) Rbuf[rbase + (size_t)(10 + i) * 512] = f2bf(s8[i]);
    }
  }
}

// ---------------------------------------------------------------------------
// K2F: reduce Rbuf over h within each pyramid h-bin -> Pt/Pg [b][128 s][256].
// ---------------------------------------------------------------------------
__global__ __launch_bounds__(256) void k2_pool_final(
    const unsigned short* __restrict__ Rbuf, float* __restrict__ Pt,
    float* __restrict__ Pg)
{
  const int s = blockIdx.x, b = blockIdx.y, tid = threadIdx.x;
  size_t obase = ((size_t)(b * 128) + s) * 256 + tid;
  if (s >= 110) { Pt[obase] = 0.f; Pg[obase] = 0.f; return; }
  int he, wb;
  if (s == 0)      { he = 0; wb = 0; }
  else if (s < 10) { int i = s - 1;  he = 1 + i / 3;  wb = 1 + i % 3; }
  else if (s < 46) { int i = s - 10; he = 4 + i / 6;  wb = 4 + i % 6; }
  else             { int i = s - 46; he = 10 + i / 8; wb = 10 + i % 8; }
  float m0 = -3.4e38f, m1 = -3.4e38f;
  int e = c_RE[he];
  for (int h = c_RS[he]; h < e; ++h) {
    const unsigned short* r = Rbuf + (((size_t)(b * 64 + h)) * 18 + wb) * 512;
    m0 = fmaxf(m0, bf2f(r[tid]));
    m1 = fmaxf(m1, bf2f(r[tid + 256]));
  }
  Pt[obase] = m0;
  Pg[obase] = m1;
}

// ---------------------------------------------------------------------------
// K3 (fused kmat+vmat, blockIdx.z selects):
//  z=0: Kt[b,s,c] = sum_ic w_phi[ic,c]*Pt[b,s,ic] -> hi/lo bf16 split
//  z=1: Vb[b,o,s] = bf16( sum_ic w_mask[o,ic]*Pg[b,s,ic] )
// ---------------------------------------------------------------------------
__global__ __launch_bounds__(256) void k3_fused(
    const float* __restrict__ Pt, const float* __restrict__ Pg,
    const float* __restrict__ w_phi, const float* __restrict__ w_mask,
    unsigned short* __restrict__ Kth, unsigned short* __restrict__ Ktl,
    unsigned short* __restrict__ Vb)
{
  __shared__ __align__(16) char sm3[51200];
  const int tid = threadIdx.x;
  const int tx = tid & 15, ty = tid >> 4;
  const int b = blockIdx.y;
  if (blockIdx.z == 0) {
    const int ct = blockIdx.x;
    const int c0 = tx * 4, s0 = ty * 8;
    float* Ls = (float*)sm3;            // [128][64]
    float* Ws = Ls + 128 * 64;          // [64][68]
    float acc[8][4] = {};
    for (int kc = 0; kc < 256; kc += 64) {
      #pragma unroll
      for (int j = 0; j < 8; ++j) {
        int flat = tid + 256 * j;
        int row = flat >> 4, k4 = (flat & 15) << 2;
        *(float4*)&Ls[row * 64 + k4] =
            *(const float4*)(Pt + ((size_t)(b * 128) + row) * 256 + kc + k4);
      }
      #pragma unroll
      for (int j = 0; j < 4; ++j) {
        int flat = tid + 256 * j;
        int row = flat >> 4, cc4 = (flat & 15) << 2;
        *(float4*)&Ws[row * 68 + cc4] =
            *(const float4*)(w_phi + (size_t)(kc + row) * 512 + ct * 64 + cc4);
      }
      __syncthreads();
      for (int k = 0; k < 64; k += 4) {
        float4 wv[4];
        #pragma unroll
        for (int kk = 0; kk < 4; ++kk) wv[kk] = *(const float4*)&Ws[(k + kk) * 68 + c0];
        #pragma unroll
        for (int i = 0; i < 8; ++i) {
          float4 a = *(const float4*)&Ls[(s0 + i) * 64 + k];
          const float* ap = (const float*)&a;
          #pragma unroll
          for (int kk = 0; kk < 4; ++kk) {
            const float* wp = (const float*)&wv[kk];
            acc[i][0] += ap[kk] * wp[0];
            acc[i][1] += ap[kk] * wp[1];
            acc[i][2] += ap[kk] * wp[2];
            acc[i][3] += ap[kk] * wp[3];
          }
        }
      }
      __syncthreads();
    }
    #pragma unroll
    for (int i = 0; i < 8; ++i) {
      unsigned short hi[4]; float lo[4];
      #pragma unroll
      for (int j = 0; j < 4; ++j) { hi[j] = f2bf(acc[i][j]); lo[j] = acc[i][j] - bf2f(hi[j]); }
      size_t base = ((size_t)(b * 128) + s0 + i) * 512 + ct * 64 + c0;
      uint2 uh; uh.x = (unsigned)hi[0] | ((unsigned)hi[1] << 16);
      uh.y = (unsigned)hi[2] | ((unsigned)hi[3] << 16);
      uint2 ul; ul.x = pack2(lo[0], lo[1]); ul.y = pack2(lo[2], lo[3]);
      *(uint2*)&Kth[base] = uh;
      *(uint2*)&Ktl[base] = ul;
    }
  } else {
    const int ot = blockIdx.x;
    const int o0 = ty * 4;
    float* Ws = (float*)sm3;            // [64][64]
    float* Ps = Ws + 64 * 64;           // [128][68]
    float acc[4][8] = {};
    for (int kc = 0; kc < 256; kc += 64) {
      #pragma unroll
      for (int j = 0; j < 4; ++j) {
        int flat = tid + 256 * j;
        int row = flat >> 4, k4 = (flat & 15) << 2;
        *(float4*)&Ws[row * 64 + k4] =
            *(const float4*)(w_mask + (size_t)(ot * 64 + row) * 256 + kc + k4);
      }
      #pragma unroll
      for (int j = 0; j < 8; ++j) {
        int flat = tid + 256 * j;
        int row = flat >> 4, k4 = (flat & 15) << 2;
        *(float4*)&Ps[row * 68 + k4] =
            *(const float4*)(Pg + ((size_t)(b * 128) + row) * 256 + kc + k4);
      }
      __syncthreads();
      for (int k = 0; k < 64; k += 4) {
        float4 wv[4];
        #pragma unroll
        for (int i = 0; i < 4; ++i) wv[i] = *(const float4*)&Ws[(o0 + i) * 64 + k];
        #pragma unroll
        for (int jj = 0; jj < 8; ++jj) {
          float4 pv = *(const float4*)&Ps[(tx + 16 * jj) * 68 + k];
          const float* pp = (const float*)&pv;
          #pragma unroll
          for (int i = 0; i < 4; ++i) {
            const float* wp = (const float*)&wv[i];
            #pragma unroll
            for (int kk = 0; kk < 4; ++kk) acc[i][jj] += wp[kk] * pp[kk];
          }
        }
      }
      __syncthreads();
    }
    #pragma unroll
    for (int i = 0; i < 4; ++i)
      #pragma unroll
      for (int jj = 0; jj < 8; ++jj)
        Vb[((size_t)(b * 512) + ot * 64 + o0 + i) * 128 + tx + 16 * jj] =
            f2bf(acc[i][jj]);
  }
}

// ---------------------------------------------------------------------------
// K4: scoresT[b,n,s] = sum_c Kt[b,s,c]*x[b,c,n]; Kt hi/lo split (2 MFMAs).
// 2 LDS buffers + SmP/SsP unioned (53.2 KB -> 3 blocks/CU), counted vmcnt,
// stage after barrier, x prefetched 3 tiles ahead.
// ---------------------------------------------------------------------------
__global__ __launch_bounds__(256) void k4_scores(
    const float* __restrict__ x, const unsigned short* __restrict__ Kth,
    const unsigned short* __restrict__ Ktl, float* __restrict__ scoresT,
    float* __restrict__ pmax_g, float* __restrict__ psum_g)
{
  const int tid = threadIdx.x;
  const int ntile = blockIdx.x;
  const int nb = ntile * 128;
  const int b = blockIdx.y;
  const int lane = tid & 63, wv = tid >> 6;
  const int wm = (wv & 1) * 64, wn = (wv >> 1) * 64;
  const int l15 = lane & 15, l4 = lane >> 4;
  // per buffer: Ah 8192 | Al 8192 | Bs [128][40] 10240 -> 26624 B
  __shared__ __align__(16) char smem4[2 * 26624];   // 53248 B
  float* SmP = (float*)smem4;        // reused after K-loop (256 f)
  float* SsP = SmP + 256;

  const int c4 = tid & 7, n4 = tid >> 3;
  const float* xcol = x + ((size_t)(b * 512)) * 4096 + nb + n4 * 4;

  f32x4 acc[4][4];
  #pragma unroll
  for (int i = 0; i < 4; ++i)
    #pragma unroll
    for (int j = 0; j < 4; ++j) acc[i][j] = f32x4{0.f, 0.f, 0.f, 0.f};

  float xr[3][16];
  auto xload = [&](float* xrp, int kb) {
    #pragma unroll
    for (int cc = 0; cc < 4; ++cc)
      *(float4*)&xrp[cc * 4] =
          *(const float4*)(xcol + (size_t)(kb + c4 * 4 + cc) * 4096);
  };
  auto dmaA = [&](int buf, int kb) {
    unsigned short* Ah = (unsigned short*)(smem4 + buf * 26624);
    unsigned short* Al = Ah + 4096;
    #pragma unroll
    for (int p = 0; p < 2; ++p) {
      int chunk = (wv * 2 + p) * 64 + lane;
      int row = chunk >> 2, cc16 = chunk & 3;
      size_t g = ((size_t)(b * 128) + row) * 512 + kb + cc16 * 8;
      gl_lds16(Kth + g, Ah + (wv * 2 + p) * 512);
      gl_lds16(Ktl + g, Al + (wv * 2 + p) * 512);
    }
  };
  auto bwrite = [&](int buf, const float* xrp) {
    unsigned short* Bs = (unsigned short*)(smem4 + buf * 26624 + 16384);
    #pragma unroll
    for (int q = 0; q < 4; ++q) {
      uint2 u;
      u.x = pack2(xrp[q], xrp[4 + q]);
      u.y = pack2(xrp[8 + q], xrp[12 + q]);
      *(uint2*)&Bs[(n4 * 4 + q) * 40 + c4 * 4] = u;
    }
  };
  auto mfma_step = [&](int buf) {
    const unsigned short* Ah = (const unsigned short*)(smem4 + buf * 26624);
    const unsigned short* Al = Ah + 4096;
    const unsigned short* Bs = Al + 4096;
    bf16x8 ah[4], al[4], bfr[4];
    #pragma unroll
    for (int i = 0; i < 4; ++i) {
      ah[i] = *(const bf16x8*)&Ah[(wm + i * 16 + l15) * 32 + l4 * 8];
      al[i] = *(const bf16x8*)&Al[(wm + i * 16 + l15) * 32 + l4 * 8];
    }
    #pragma unroll
    for (int j = 0; j < 4; ++j)
      bfr[j] = *(const bf16x8*)&Bs[(wn + j * 16 + l15) * 40 + l4 * 8];
    #pragma unroll
    for (int i = 0; i < 4; ++i)
      #pragma unroll
      for (int j = 0; j < 4; ++j) {
        acc[i][j] = __builtin_amdgcn_mfma_f32_16x16x32_bf16(ah[i], bfr[j], acc[i][j], 0, 0, 0);
        acc[i][j] = __builtin_amdgcn_mfma_f32_16x16x32_bf16(al[i], bfr[j], acc[i][j], 0, 0, 0);
      }
  };

  dmaA(0, 0);
  xload(xr[0], 0);
  xload(xr[1], 32);
  xload(xr[2], 64);
  bwrite(0, xr[0]);
  #pragma unroll
  for (int t = 0; t < 16; ++t) {
    if (t < 14) wt_vm4();
    else wt_vm0();
    __builtin_amdgcn_s_barrier();
    __builtin_amdgcn_sched_barrier(0);
    if (t + 1 < 16) dmaA((t + 1) & 1, (t + 1) * 32);
    if (t + 3 < 16) xload(xr[t % 3], (t + 3) * 32);
    mfma_step(t & 1);
    if (t + 1 < 16) bwrite((t + 1) & 1, xr[(t + 1) % 3]);
  }

  // scoresT store: n row = nb+wn+j*16+l15, s base = wm+i*16+l4*4 (float4 in s)
  #pragma unroll
  for (int i = 0; i < 4; ++i)
    #pragma unroll
    for (int j = 0; j < 4; ++j)
      *(float4*)(scoresT + ((size_t)(b * 4096) + nb + wn + j * 16 + l15) * 128 +
                 wm + i * 16 + l4 * 4) = *(float4*)&acc[i][j];

  // Softmax partials for this 128s x 128n tile (SmP/SsP live in buf0 region;
  // last tile (15) was read from buf1 -> disjoint; __syncthreads before read).
  const int nh = wn >> 6;
  float cm[4][4];
  #pragma unroll
  for (int i = 0; i < 4; ++i)
    #pragma unroll
    for (int r = 0; r < 4; ++r) {
      float v = fmaxf(fmaxf(acc[i][0][r], acc[i][1][r]),
                      fmaxf(acc[i][2][r], acc[i][3][r]));
      v = fmaxf(v, __shfl_xor(v, 1));
      v = fmaxf(v, __shfl_xor(v, 2));
      v = fmaxf(v, __shfl_xor(v, 4));
      v = fmaxf(v, __shfl_xor(v, 8));
      if (l15 == 0) SmP[(wm + i * 16 + l4 * 4 + r) * 2 + nh] = v;
    }
  __syncthreads();
  #pragma unroll
  for (int i = 0; i < 4; ++i)
    #pragma unroll
    for (int r = 0; r < 4; ++r) {
      int s = wm + i * 16 + l4 * 4 + r;
      cm[i][r] = fmaxf(SmP[s * 2], SmP[s * 2 + 1]);
    }
  #pragma unroll
  for (int i = 0; i < 4; ++i)
    #pragma unroll
    for (int r = 0; r < 4; ++r) {
      float s0 = __expf(acc[i][0][r] - cm[i][r]) + __expf(acc[i][1][r] - cm[i][r]) +
                 __expf(acc[i][2][r] - cm[i][r]) + __expf(acc[i][3][r] - cm[i][r]);
      s0 += __shfl_xor(s0, 1);
      s0 += __shfl_xor(s0, 2);
      s0 += __shfl_xor(s0, 4);
      s0 += __shfl_xor(s0, 8);
      if (l15 == 0) SsP[(wm + i * 16 + l4 * 4 + r) * 2 + nh] = s0;
    }
  __syncthreads();
  if (tid < 128) {
    size_t pidx = ((size_t)(b * 128) + tid) * 32 + ntile;
    pmax_g[pidx] = fmaxf(SmP[tid * 2], SmP[tid * 2 + 1]);
    psum_g[pidx] = SsP[tid * 2] + SsP[tid * 2 + 1];
  }
}

// ---------------------------------------------------------------------------
// K5E: combine per-tile partials -> (m, 1/sum) per (b,s), then stream
// Eb[b,n,s] = bf16( exp(scoresT[b,n,s]-m[s]) * linv[s] ).
// ---------------------------------------------------------------------------
__global__ __launch_bounds__(256) void k5e_exp(
    const float* __restrict__ scoresT, const float* __restrict__ pmax_g,
    const float* __restrict__ psum_g, unsigned short* __restrict__ Eb)
{
  const int b = blockIdx.y, tid = threadIdx.x;
  __shared__ float sm[128], sl[128];
  if (tid < 128) {
    float M = 0.f, linv = 0.f;
    if (tid < 110) {
      const float* pm = pmax_g + ((size_t)(b * 128) + tid) * 32;
      const float* ps = psum_g + ((size_t)(b * 128) + tid) * 32;
      M = -3.4e38f;
      #pragma unroll
      for (int t = 0; t < 32; ++t) M = fmaxf(M, pm[t]);
      float S = 0.f;
      #pragma unroll
      for (int t = 0; t < 32; ++t) S += ps[t] * __expf(pm[t] - M);
      linv = 1.f / S;
    }
    sm[tid] = M; sl[tid] = linv;
  }
  __syncthreads();
  const size_t base = (size_t)b * 4096 * 128;
  #pragma unroll
  for (int j = 0; j < 8; ++j) {
    int chunk = blockIdx.x * 2048 + j * 256 + tid;   // float4 id within b
    int sc = (chunk & 31) * 4;
    float4 v = *(const float4*)(scoresT + base + (size_t)chunk * 4);
    float e0 = __expf(v.x - sm[sc])     * sl[sc];
    float e1 = __expf(v.y - sm[sc + 1]) * sl[sc + 1];
    float e2 = __expf(v.z - sm[sc + 2]) * sl[sc + 2];
    float e3 = __expf(v.w - sm[sc + 3]) * sl[sc + 3];
    uint2 u; u.x = pack2(e0, e1); u.y = pack2(e2, e3);
    *(uint2*)(Eb + base + (size_t)chunk * 4) = u;
  }
}

// ---------------------------------------------------------------------------
// K6: out[b,o,n] = sum_s Vb[b,o,s] * Eb[b,n,s] + x[b,o,n]
// Whole K=128 staged at once (ONE barrier); x prefetched into VGPRs while
// the LDS-DMA is in flight. XCD-chunked tile swizzle for Eb L2 reuse.
// ---------------------------------------------------------------------------
__global__ __launch_bounds__(256) void k6_out(
    const unsigned short* __restrict__ Eb, const unsigned short* __restrict__ Vb,
    const float* __restrict__ x, float* __restrict__ out)
{
  const int tid = threadIdx.x;
  const int id = blockIdx.x;
  const int tile = (id & 7) * 16 + (id >> 3);   // XCD-chunked, bijective
  const int mb = (tile & 3) * 128;
  const int nb = (tile >> 2) * 128;
  const int b = blockIdx.y;
  const int lane = tid & 63, wv = tid >> 6;
  const int wm = (wv & 1) * 64, wn = (wv >> 1) * 64;
  const int l15 = lane & 15, l4 = lane >> 4;
  __shared__ __align__(16) unsigned short SA[4][4096];   // 32 KB
  __shared__ __align__(16) unsigned short SB[4][4096];   // 32 KB

  #pragma unroll
  for (int h = 0; h < 4; ++h)
    #pragma unroll
    for (int p = 0; p < 2; ++p) {
      int chunk = (wv * 2 + p) * 64 + lane;
      int row = chunk >> 2, c16 = chunk & 3;
      gl_lds16(Vb + ((size_t)(b * 512) + mb + row) * 128 + h * 32 + c16 * 8,
               &SA[h][(wv * 2 + p) * 512]);
      gl_lds16(Eb + ((size_t)(b * 4096) + nb + row) * 128 + h * 32 + c16 * 8,
               &SB[h][(wv * 2 + p) * 512]);
    }

  float xr[4][4][4];
  #pragma unroll
  for (int i = 0; i < 4; ++i)
    #pragma unroll
    for (int j = 0; j < 4; ++j)
      #pragma unroll
      for (int r = 0; r < 4; ++r)
        xr[i][j][r] = x[((size_t)(b * 512) + mb + wm + i * 16 + l4 * 4 + r) * 4096 +
                        nb + wn + j * 16 + l15];

  f32x4 acc[4][4];
  #pragma unroll
  for (int i = 0; i < 4; ++i)
    #pragma unroll
    for (int j = 0; j < 4; ++j) acc[i][j] = f32x4{0.f, 0.f, 0.f, 0.f};

  __syncthreads();
  #pragma unroll
  for (int h = 0; h < 4; ++h) {
    bf16x8 af[4], bfr[4];
    #pragma unroll
    for (int i = 0; i < 4; ++i)
      af[i] = *(const bf16x8*)&SA[h][(wm + i * 16 + l15) * 32 + l4 * 8];
    #pragma unroll
    for (int j = 0; j < 4; ++j)
      bfr[j] = *(const bf16x8*)&SB[h][(wn + j * 16 + l15) * 32 + l4 * 8];
    #pragma unroll
    for (int i = 0; i < 4; ++i)
      #pragma unroll
      for (int j = 0; j < 4; ++j)
        acc[i][j] = __builtin_amdgcn_mfma_f32_16x16x32_bf16(af[i], bfr[j], acc[i][j], 0, 0, 0);
  }
  #pragma unroll
  for (int i = 0; i < 4; ++i)
    #pragma unroll
    for (int j = 0; j < 4; ++j)
      #pragma unroll
      for (int r = 0; r < 4; ++r) {
        int o = mb + wm + i * 16 + l4 * 4 + r;
        size_t idx = ((size_t)(b * 512) + o) * 4096 + nb + wn + j * 16 + l15;
        out[idx] = acc[i][j][r] + xr[i][j][r];
      }
}

// ---------------------------------------------------------------------------
extern "C" void kernel_launch(void* const* d_in, const int* in_sizes, int n_in,
                              void* d_out, int out_size, void* d_ws, size_t ws_size,
                              hipStream_t stream)
{
  (void)in_sizes; (void)n_in; (void)out_size; (void)ws_size;
  const float* x       = (const float*)d_in[0];
  const float* y       = (const float*)d_in[1];
  const float* w_phi   = (const float*)d_in[2];
  const float* w_theta = (const float*)d_in[3];
  const float* w_g     = (const float*)d_in[4];
  const float* w_mask  = (const float*)d_in[5];
  float* out = (float*)d_out;

  char* ws = (char*)d_ws;
  char* B0 = ws + 67108864;
  unsigned short* Rbuf = (unsigned short*)B0;                 // 18874368 B
  float* scoresT = (float*)B0;                                // 33554432 B (after k2)
  unsigned short* Eb = (unsigned short*)(B0 + 33554432);      // 16777216 B
  unsigned short* wTG = (unsigned short*)(B0 + 50331648);     // 524288 B (pw->k1f)
  unsigned short* Vb  = (unsigned short*)(B0 + 50331648);     // 2097152 B (k3->k6)
  float* pmax_g = (float*)(B0 + 52428800);                    // 262144 B (k4->k5e)
  float* psum_g = (float*)(B0 + 52690944);                    // 262144 B (k4->k5e)
  char* C0 = B0 + 54525952;
  float* Pt = (float*)C0;                                     // 2097152
  float* Pg = (float*)(C0 + 2097152);                         // 2097152
  unsigned short* Kth = (unsigned short*)(C0 + 4194304);      // 2097152
  unsigned short* Ktl = (unsigned short*)(C0 + 6291456);      // 2097152

  pw_conv<<<dim3(128), 256, 0, stream>>>(w_theta, w_g, wTG);
  k1f_conv_pool<<<dim3(128, 16), 256, 0, stream>>>(y, wTG, Rbuf);
  k2_pool_final<<<dim3(128, 16), 256, 0, stream>>>(Rbuf, Pt, Pg);
  k3_fused<<<dim3(8, 16, 2), 256, 0, stream>>>(Pt, Pg, w_phi, w_mask, Kth, Ktl, Vb);
  k4_scores<<<dim3(32, 16), 256, 0, stream>>>(x, Kth, Ktl, scoresT, pmax_g, psum_g);
  k5e_exp<<<dim3(64, 16), 256, 0, stream>>>(scoresT, pmax_g, psum_g, Eb);
  k6_out<<<dim3(128, 16), 256, 0, stream>>>(Eb, Vb, x, out);
}